// Round 1
// baseline (9235.077 us; speedup 1.0000x reference)
//
#include <hip/hip_runtime.h>

// ---------------------------------------------------------------------------
// LSTM layer, T=512 B=64 D=H=1024, output = h_T (64x1024 fp32).
// Strategy:
//   prep: cast x -> bf16 [T*B,1024]; transpose-cast W_g,R_g -> WtT/RtT [4096][1024] bf16
//         (gate order i,f,o,c to match reference concat [W_i,W_f,W_o,W_c])
//   main: ONE persistent kernel, 128 blocks x 256 threads, all co-resident.
//         Block b owns 8 hidden units (32 g-columns). W,R column slices live in
//         LDS (2 x 64.5 KB). Per step: g = x_t@W (no sync needed) + h@R (after
//         device-scope flag barrier) + b; gates in fp32; c in registers; h_t
//         round-tripped through a double-buffered global bf16 buffer.
// ---------------------------------------------------------------------------

typedef __attribute__((ext_vector_type(8))) short     short8;   // 8 bf16 = 4 VGPRs (MFMA A/B frag)
typedef __attribute__((ext_vector_type(4))) float     f32x4;    // MFMA C/D frag
typedef __attribute__((ext_vector_type(8))) unsigned short ushort8v;
typedef __attribute__((ext_vector_type(4))) unsigned short ushort4v;

__device__ __forceinline__ unsigned short f2bf(float f) {
  unsigned int u = __float_as_uint(f);
  u += 0x7FFFu + ((u >> 16) & 1u);          // RNE
  return (unsigned short)(u >> 16);
}

// ---------------- prep 1: cast x (fp32, 33.5M elems) -> bf16, zero flags ----
__global__ void k_cast_x(const float* __restrict__ x, unsigned short* __restrict__ xb,
                         int* __restrict__ flags) {
  long i = ((long)blockIdx.x * 256 + threadIdx.x) * 8;
  f32x4 a = *(const f32x4*)(x + i);
  f32x4 b = *(const f32x4*)(x + i + 4);
  ushort8v o;
  o[0] = f2bf(a[0]); o[1] = f2bf(a[1]); o[2] = f2bf(a[2]); o[3] = f2bf(a[3]);
  o[4] = f2bf(b[0]); o[5] = f2bf(b[1]); o[6] = f2bf(b[2]); o[7] = f2bf(b[3]);
  *(ushort8v*)(xb + i) = o;
  if (blockIdx.x == 0) flags[threadIdx.x] = 0;   // 256 ints: ws is poisoned 0xAA each launch
}

// ---------------- prep 2: transpose-cast one 1024x1024 fp32 -> dst[n][k] bf16
__global__ void k_tcast(const float* __restrict__ src, unsigned short* __restrict__ dst) {
  __shared__ unsigned short tile[64][65];
  const int k0 = blockIdx.x << 6;
  const int n0 = blockIdx.y << 6;
  const int tid = threadIdx.x;
#pragma unroll
  for (int i = 0; i < 4; ++i) {
    int q = tid + (i << 8);
    int r = q >> 4, c4 = (q & 15) << 2;
    f32x4 v = *(const f32x4*)(src + (size_t)(k0 + r) * 1024 + n0 + c4);
    tile[r][c4 + 0] = f2bf(v[0]);
    tile[r][c4 + 1] = f2bf(v[1]);
    tile[r][c4 + 2] = f2bf(v[2]);
    tile[r][c4 + 3] = f2bf(v[3]);
  }
  __syncthreads();
#pragma unroll
  for (int i = 0; i < 4; ++i) {
    int q = tid + (i << 8);
    int rn = q >> 4, kc = (q & 15) << 2;
    ushort4v o;
    o[0] = tile[kc + 0][rn];
    o[1] = tile[kc + 1][rn];
    o[2] = tile[kc + 2][rn];
    o[3] = tile[kc + 3][rn];
    *(ushort4v*)(dst + (size_t)(n0 + rn) * 1024 + k0 + kc) = o;
  }
}

// ---------------- main: persistent recurrence -------------------------------
#define NB 128           // blocks; all co-resident on 256 CUs (141 KB LDS -> 1 block/CU)
#define LDP 1032         // padded row length (bf16 elems): 2-way LDS bank aliasing only

__global__ __launch_bounds__(256, 1) void k_lstm(
    const unsigned short* __restrict__ xb,    // [512*64][1024] bf16
    const unsigned short* __restrict__ WtT,   // [4096][1024] bf16, n = gate*1024+u
    const unsigned short* __restrict__ RtT,
    const float* __restrict__ b_i, const float* __restrict__ b_f,
    const float* __restrict__ b_o, const float* __restrict__ b_c,
    const float* __restrict__ s0, const float* __restrict__ c0,
    unsigned short* __restrict__ h_buf,       // [2][64*1024] bf16 double buffer
    int* __restrict__ flags, float* __restrict__ out) {
  __shared__ unsigned short Wl[32 * LDP];   // 64.5 KB: W columns for this block
  __shared__ unsigned short Rl[32 * LDP];   // 64.5 KB
  __shared__ float gl[64 * 33];             // 8.25 KB: pre-activation exchange
  __shared__ float bias[32];
  const int tid = threadIdx.x;
  const int bid = blockIdx.x;
  const int u0 = bid << 3;                  // 8 hidden units per block

  // one-time: load W,R column slices into LDS (cc = gate*8+u, row = 1024 bf16)
  for (int q = tid; q < 4096; q += 256) {
    int cc = q >> 7, ch = q & 127;
    int n = ((cc >> 3) << 10) + u0 + (cc & 7);
    *(short8*)(&Wl[cc * LDP + ch * 8]) = *(const short8*)(WtT + (size_t)n * 1024 + ch * 8);
    *(short8*)(&Rl[cc * LDP + ch * 8]) = *(const short8*)(RtT + (size_t)n * 1024 + ch * 8);
  }
  if (tid < 32) {
    const float* bp = (tid < 8) ? b_i : (tid < 16) ? b_f : (tid < 24) ? b_o : b_c;
    bias[tid] = bp[u0 + (tid & 7)];
  }
  // state: thread owns (b,u) pairs p0=tid, p1=tid+256; p = b*8+u
  const int pu = tid & 7;
  const int pb0 = tid >> 3, pb1 = (tid + 256) >> 3;
  const int ia0 = pb0 * 1024 + u0 + pu;
  const int ia1 = pb1 * 1024 + u0 + pu;
  float cA = c0[ia0], cB = c0[ia1];
  h_buf[ia0] = f2bf(s0[ia0]);
  h_buf[ia1] = f2bf(s0[ia1]);
  __syncthreads();
  if (tid == 0) __hip_atomic_store(&flags[bid], 1, __ATOMIC_RELEASE, __HIP_MEMORY_SCOPE_AGENT);

  // MFMA lane geometry (16x16x32 bf16): A[m=lane&15][k=quad*8+j], B[k][n=lane&15],
  // D col=lane&15, row=quad*4+r  (guide-verified layouts)
  const int wv = tid >> 6, ln = tid & 63;
  const int mrow = (wv << 4) + (ln & 15);   // batch row this lane contributes to
  const int quad = ln >> 4, ncol = ln & 63 & 15;
  const unsigned short* Wf0 = &Wl[(ncol)*LDP + quad * 8];
  const unsigned short* Wf1 = &Wl[(16 + ncol) * LDP + quad * 8];
  const unsigned short* Rf0 = &Rl[(ncol)*LDP + quad * 8];
  const unsigned short* Rf1 = &Rl[(16 + ncol) * LDP + quad * 8];

  for (int t = 0; t < 512; ++t) {
    f32x4 acc0 = {0.f, 0.f, 0.f, 0.f};
    f32x4 acc1 = {0.f, 0.f, 0.f, 0.f};
    // ---- x_t @ W half: no inter-block dependency, runs BEFORE the barrier ----
    const unsigned short* xt = xb + ((size_t)((t << 6) + mrow) << 10) + (quad << 3);
#pragma unroll
    for (int kk = 0; kk < 32; ++kk) {
      short8 a  = *(const short8*)(xt + kk * 32);
      short8 w0 = *(const short8*)(Wf0 + kk * 32);
      short8 w1 = *(const short8*)(Wf1 + kk * 32);
      acc0 = __builtin_amdgcn_mfma_f32_16x16x32_bf16(a, w0, acc0, 0, 0, 0);
      acc1 = __builtin_amdgcn_mfma_f32_16x16x32_bf16(a, w1, acc1, 0, 0, 0);
    }
    // ---- wait for h_t from all blocks (relaxed poll + acquire fence) ----
    if (tid < NB) {
      while (__hip_atomic_load(&flags[tid], __ATOMIC_RELAXED, __HIP_MEMORY_SCOPE_AGENT) < t + 1)
        __builtin_amdgcn_s_sleep(2);
      __threadfence();
    }
    __syncthreads();
    // ---- h_t @ R half ----
    const unsigned short* hc = h_buf + ((size_t)(t & 1) << 16) + ((size_t)mrow << 10) + (quad << 3);
#pragma unroll
    for (int kk = 0; kk < 32; ++kk) {
      short8 a  = *(const short8*)(hc + kk * 32);
      short8 r0 = *(const short8*)(Rf0 + kk * 32);
      short8 r1 = *(const short8*)(Rf1 + kk * 32);
      acc0 = __builtin_amdgcn_mfma_f32_16x16x32_bf16(a, r0, acc0, 0, 0, 0);
      acc1 = __builtin_amdgcn_mfma_f32_16x16x32_bf16(a, r1, acc1, 0, 0, 0);
    }
    // ---- exchange pre-activations through LDS ----
    {
      int grow = (wv << 4) + (quad << 2);
#pragma unroll
      for (int r = 0; r < 4; ++r) {
        gl[(grow + r) * 33 + ncol] = acc0[r];
        gl[(grow + r) * 33 + 16 + ncol] = acc1[r];
      }
    }
    __syncthreads();
    // ---- gates (fp32), state update, publish h_{t+1} ----
    unsigned short* hn = h_buf + ((size_t)((t + 1) & 1) << 16);
#pragma unroll
    for (int s = 0; s < 2; ++s) {
      int b = (s == 0) ? pb0 : pb1;
      float gi = gl[b * 33 + pu]      + bias[pu];
      float gf = gl[b * 33 + 8 + pu]  + bias[8 + pu];
      float go = gl[b * 33 + 16 + pu] + bias[16 + pu];
      float gc = gl[b * 33 + 24 + pu] + bias[24 + pu];
      // reference: sigmoid(x) = (tanh(x)+1)/2 ; c_hat = tanh(gc)
      float it = 0.5f * (tanhf(gi) + 1.0f);
      float ft = 0.5f * (tanhf(gf) + 1.0f);
      float ot = 0.5f * (tanhf(go) + 1.0f);
      float ch = tanhf(gc);
      float c  = (s == 0) ? cA : cB;
      c = ft * c + it * ch;
      if (s == 0) cA = c; else cB = c;
      float h = ot * tanhf(c);
      int idx = b * 1024 + u0 + pu;
      hn[idx] = f2bf(h);
      if (t == 511) out[idx] = h;
    }
    __syncthreads();   // all h-writes of this block done
    if (tid == 0) __hip_atomic_store(&flags[bid], t + 2, __ATOMIC_RELEASE, __HIP_MEMORY_SCOPE_AGENT);
  }
}

// ---------------------------------------------------------------------------
extern "C" void kernel_launch(void* const* d_in, const int* in_sizes, int n_in,
                              void* d_out, int out_size, void* d_ws, size_t ws_size,
                              hipStream_t stream) {
  const float* x   = (const float*)d_in[0];
  const float* W_i = (const float*)d_in[1];
  const float* W_f = (const float*)d_in[2];
  const float* W_c = (const float*)d_in[3];
  const float* W_o = (const float*)d_in[4];
  const float* R_i = (const float*)d_in[5];
  const float* R_f = (const float*)d_in[6];
  const float* R_c = (const float*)d_in[7];
  const float* R_o = (const float*)d_in[8];
  const float* b_i = (const float*)d_in[9];
  const float* b_f = (const float*)d_in[10];
  const float* b_c = (const float*)d_in[11];
  const float* b_o = (const float*)d_in[12];
  const float* s0  = (const float*)d_in[13];
  const float* c0  = (const float*)d_in[14];
  float* out = (float*)d_out;

  char* ws = (char*)d_ws;
  unsigned short* xb   = (unsigned short*)(ws);                               // 64 MB
  unsigned short* WtT  = (unsigned short*)(ws + (size_t)67108864);            // 8 MB
  unsigned short* RtT  = (unsigned short*)(ws + (size_t)67108864 + 8388608);  // 8 MB
  unsigned short* hbuf = (unsigned short*)(ws + (size_t)67108864 + 16777216); // 256 KB
  int* flags           = (int*)(ws + (size_t)67108864 + 16777216 + 262144);   // 1 KB

  k_cast_x<<<16384, 256, 0, stream>>>(x, xb, flags);
  // gate order i,f,o,c (reference concatenates [*_i, *_f, *_o, *_c])
  dim3 tg(16, 16);
  k_tcast<<<tg, 256, 0, stream>>>(W_i, WtT + 0);
  k_tcast<<<tg, 256, 0, stream>>>(W_f, WtT + 1048576);
  k_tcast<<<tg, 256, 0, stream>>>(W_o, WtT + 2097152);
  k_tcast<<<tg, 256, 0, stream>>>(W_c, WtT + 3145728);
  k_tcast<<<tg, 256, 0, stream>>>(R_i, RtT + 0);
  k_tcast<<<tg, 256, 0, stream>>>(R_f, RtT + 1048576);
  k_tcast<<<tg, 256, 0, stream>>>(R_o, RtT + 2097152);
  k_tcast<<<tg, 256, 0, stream>>>(R_c, RtT + 3145728);

  k_lstm<<<NB, 256, 0, stream>>>(xb, WtT, RtT, b_i, b_f, b_o, b_c, s0, c0, hbuf, flags, out);
}